// Round 2
// baseline (361.975 us; speedup 1.0000x reference)
//
#include <hip/hip_runtime.h>

#define S_Q 2048
#define S_KV 2048
#define D_K 128
#define NH 64
#define NB 4
// (1/sqrt(128)) * log2(e): fold softmax scale AND exp->exp2 conversion into Q
#define QSCALE 0.12751494907890272f

typedef __attribute__((ext_vector_type(8))) short s16x8;
typedef __attribute__((ext_vector_type(16))) float f32x16;

__device__ __attribute__((aligned(16))) unsigned short g_Kb[(size_t)NH * S_KV * D_K];
__device__ __attribute__((aligned(16))) unsigned short g_Vt[(size_t)NH * D_K * S_KV];
__device__ __attribute__((aligned(16))) unsigned short g_kpmf[NB * S_KV];  // 1.0/0.0 bf16

__device__ inline unsigned short f2bf(float f) {
  unsigned int u = __float_as_uint(f);
  u += 0x7FFFu + ((u >> 16) & 1u);  // RNE
  return (unsigned short)(u >> 16);
}

// RNE pack two f32 -> one dword of 2x bf16 (lo = first arg)
__device__ inline unsigned cvt_pk_bf16(float lo, float hi) {
  unsigned r;
  asm("v_cvt_pk_bf16_f32 %0, %1, %2" : "=v"(r) : "v"(lo), "v"(hi));
  return r;
}

// v_permlane32_swap_b32: first.hi(lanes32-63) <-> second.lo(lanes0-31)
__device__ inline void plane32_swap(unsigned& a, unsigned& b) {
#if __has_builtin(__builtin_amdgcn_permlane32_swap)
  typedef unsigned __attribute__((ext_vector_type(2))) u32x2;
  u32x2 r = __builtin_amdgcn_permlane32_swap(a, b, false, false);
  a = r.x; b = r.y;
#else
  asm volatile("v_permlane32_swap_b32 %0, %1" : "+v"(a), "+v"(b));
#endif
}

// ---------------- prep 1: K fp32 -> bf16, same layout; plus kpm -> bf16 weights ----------------
__global__ __launch_bounds__(256) void prep_k_kernel(const float* __restrict__ K,
                                                     const int* __restrict__ kpm) {
  size_t g = (size_t)blockIdx.x * 256 + threadIdx.x;
  const float* src = K + g * 8;
  float4 x = *(const float4*)src;
  float4 y = *(const float4*)(src + 4);
  union { uint4 q; unsigned short u[8]; } t;
  t.u[0] = f2bf(x.x); t.u[1] = f2bf(x.y); t.u[2] = f2bf(x.z); t.u[3] = f2bf(x.w);
  t.u[4] = f2bf(y.x); t.u[5] = f2bf(y.y); t.u[6] = f2bf(y.z); t.u[7] = f2bf(y.w);
  ((uint4*)g_Kb)[g] = t.q;
  if (g < (size_t)NB * S_KV)
    g_kpmf[g] = kpm[g] ? (unsigned short)0x3F80 : (unsigned short)0;  // bf16 1.0 / 0.0
}

// ---------------- prep 2: V fp32 -> bf16 transposed, kpm-masked rows zeroed ----------------
// block: 64 t x 32 v tile. grid = 64 bh * 32 t-tiles * 4 v-tiles = 8192
__global__ __launch_bounds__(256) void prep_v_kernel(const float* __restrict__ V,
                                                     const int* __restrict__ kpm) {
  __shared__ float tile_f[64][33];
  int bid = blockIdx.x;
  int bh = bid >> 7;
  int rem = bid & 127;
  int t0 = (rem >> 2) << 6;
  int v0 = (rem & 3) << 5;
  int c = threadIdx.x & 31;
  int r8 = threadIdx.x >> 5;  // 0..7
  const int* kp = kpm + (bh >> 4) * S_KV + t0;
#pragma unroll
  for (int i = 0; i < 8; i++) {
    int r = r8 + i * 8;
    float f = V[((size_t)(bh * S_KV + t0 + r)) * D_K + v0 + c];
    tile_f[r][c] = kp[r] ? f : 0.0f;  // fold key_padding_mask into V
  }
  __syncthreads();
  int vv = threadIdx.x >> 3;  // 0..31
  int jc = threadIdx.x & 7;   // 8-elem chunk along t
  union { uint4 q; unsigned short u[8]; } t;
#pragma unroll
  for (int u8 = 0; u8 < 8; u8++) t.u[u8] = f2bf(tile_f[jc * 8 + u8][vv]);
  *(uint4*)&g_Vt[((size_t)(bh * D_K + v0 + vv)) * S_KV + t0 + jc * 8] = t.q;
}

// ---------------- main: flash attention, S^T formulation, dbuf ----------------
// kpm folded into V + lsum-row MFMA => no per-element masking, no VALU lsum.
// Raw s_barrier with lgkmcnt-only drain: prefetch global loads stay in flight
// across the barrier (consumed by store_tile one full iteration later).
__global__ __launch_bounds__(256, 3) void attn_kernel(const float* __restrict__ Q,
                                                      float* __restrict__ out) {
  __shared__ __attribute__((aligned(16))) unsigned short sK[2][32 * 136];  // [t=32][k=128] pitch 136
  __shared__ __attribute__((aligned(16))) unsigned short sV[2][128 * 40];  // [v=128][t=32] pitch 40
  __shared__ __attribute__((aligned(16))) unsigned short sLall[S_KV];      // kpm 1.0/0.0 bf16, whole row

  const int bx = blockIdx.x;
  const int bh = ((bx & 7) << 3) | ((bx >> 3) & 7);  // same-bh q-tiles share XCD
  int qp = bx >> 6;
  // pair long+short causal tiles across dispatch batches
  int qi = (qp & 4) ? ((qp & 8) ? qp - 8 : qp - 4) : ((qp & 8) ? 19 - qp : 15 - qp);
  const int q0 = qi << 7;
  const int tid = threadIdx.x;
  const int w = tid >> 6;
  const int ln = tid & 31;
  const int h = (tid >> 5) & 1;
  const int h8 = h * 8;
  const int qw = q0 + w * 32;
  const int qln = qw + ln;
  const int b = bh >> 4;
  const unsigned short* gkpm = g_kpmf + (size_t)b * S_KV;

  // ---- Q fragments (B-operand layout == A layout; scale*log2e folded) ----
  s16x8 qf[8];
  {
    const float* qrow = Q + ((size_t)(bh * S_Q + qln)) * D_K + h8;
#pragma unroll
    for (int kc = 0; kc < 8; kc++) {
      float4 x = *(const float4*)(qrow + kc * 16);
      float4 y = *(const float4*)(qrow + kc * 16 + 4);
      union { s16x8 v; unsigned short u[8]; } t;
      t.u[0] = f2bf(x.x * QSCALE); t.u[1] = f2bf(x.y * QSCALE);
      t.u[2] = f2bf(x.z * QSCALE); t.u[3] = f2bf(x.w * QSCALE);
      t.u[4] = f2bf(y.x * QSCALE); t.u[5] = f2bf(y.y * QSCALE);
      t.u[6] = f2bf(y.z * QSCALE); t.u[7] = f2bf(y.w * QSCALE);
      qf[kc] = t.v;
    }
  }

  // ---- staging helpers (each thread: 2 uint4 for K, 2 for V) ----
  const int id0 = tid, id1 = 256 + tid;
  const int kr0r = id0 >> 4, kr0c = (id0 & 15) * 8;
  const int kr1r = id1 >> 4, kr1c = (id1 & 15) * 8;
  const int vr0r = id0 >> 2, vr0c = (id0 & 3) * 8;
  const int vr1r = id1 >> 2, vr1c = (id1 & 3) * 8;
  uint4 rk0, rk1, rv0, rv1;
  auto load_tile = [&](int t0) {
    rk0 = *(const uint4*)&g_Kb[((size_t)(bh * S_KV + t0 + kr0r)) * D_K + kr0c];
    rk1 = *(const uint4*)&g_Kb[((size_t)(bh * S_KV + t0 + kr1r)) * D_K + kr1c];
    rv0 = *(const uint4*)&g_Vt[((size_t)(bh * D_K + vr0r)) * S_KV + t0 + vr0c];
    rv1 = *(const uint4*)&g_Vt[((size_t)(bh * D_K + vr1r)) * S_KV + t0 + vr1c];
  };
  auto store_tile = [&](int buf) {
    *(uint4*)&sK[buf][kr0r * 136 + kr0c] = rk0;
    *(uint4*)&sK[buf][kr1r * 136 + kr1c] = rk1;
    *(uint4*)&sV[buf][vr0r * 40 + vr0c] = rv0;
    *(uint4*)&sV[buf][vr1r * 40 + vr1c] = rv1;
  };

  f32x16 o[4] = {f32x16{}, f32x16{}, f32x16{}, f32x16{}};
  f32x16 lacc = {};  // lsum accumulator (all 16 rows identical; col = q)

  const int nT = qi * 4 + 4;
  load_tile(0);
  store_tile(0);
  // one-time kpm weight row -> LDS (uint4 per thread covers all 2048)
  *(uint4*)&sLall[tid * 8] = *(const uint4*)(gkpm + tid * 8);
  load_tile(32);  // tile 1 -> regs
  __syncthreads();  // buf0 + sLall ready (full drain, one-time)

  for (int i = 0; i < nT; i++) {
    const int cur = i & 1;
    if (i + 1 < nT) {
      store_tile(1 - cur);               // waits vmcnt for tile i+1 regs (issued last iter)
      if (i + 2 < nT) load_tile((i + 2) * 32);  // prefetch; stays in flight across barrier
    }
    const int t0 = i * 32;
    if (t0 <= qw) {
      // S^T = K * Q^T  (A = K frag m=t, B = Q frag n=qrow)
      f32x16 sa = {};
#pragma unroll
      for (int kc = 0; kc < 8; kc++) {
        s16x8 kb = *(const s16x8*)&sK[cur][ln * 136 + kc * 16 + h8];
        sa = __builtin_amdgcn_mfma_f32_32x32x16_bf16(kb, qf[kc], sa, 0, 0, 0);
      }
      float p[16];
#pragma unroll
      for (int r = 0; r < 16; r++) p[r] = __builtin_amdgcn_exp2f(sa[r]);
      // causal zeroing only on the single diagonal tile of this warp
      if (t0 == qw) {
#pragma unroll
        for (int r = 0; r < 16; r++) {
          int tl = (r & 3) + 8 * (r >> 2) + 4 * h;  // t_local of p[r]
          if (tl > ln) p[r] = 0.0f;
        }
      }
      // RNE pack to bf16 dwords, then half-wave swap -> P^T B-frags
      unsigned d[8];
#pragma unroll
      for (int m = 0; m < 4; m++) {
        d[2 * m] = cvt_pk_bf16(p[4 * m + 0], p[4 * m + 1]);
        d[2 * m + 1] = cvt_pk_bf16(p[4 * m + 2], p[4 * m + 3]);
      }
      plane32_swap(d[0], d[2]); plane32_swap(d[1], d[3]);
      plane32_swap(d[4], d[6]); plane32_swap(d[5], d[7]);
      union { unsigned u[4]; s16x8 v; } pu0, pu1;
      pu0.u[0] = d[0]; pu0.u[1] = d[1]; pu0.u[2] = d[2]; pu0.u[3] = d[3];
      pu1.u[0] = d[4]; pu1.u[1] = d[5]; pu1.u[2] = d[6]; pu1.u[3] = d[7];
      // kpm weight row for this tile (broadcast read: all lanes same 16B -> no conflict)
      s16x8 lva0 = *(const s16x8*)&sLall[i * 32 + h8];
      s16x8 lva1 = *(const s16x8*)&sLall[i * 32 + 16 + h8];
      // O^T += V^T * P^T   (V already kpm-zeroed in prep)
#pragma unroll
      for (int vt = 0; vt < 4; vt++) {
        s16x8 va = *(const s16x8*)&sV[cur][(vt * 32 + ln) * 40 + h8];
        s16x8 vb = *(const s16x8*)&sV[cur][(vt * 32 + ln) * 40 + 16 + h8];
        o[vt] = __builtin_amdgcn_mfma_f32_32x32x16_bf16(va, pu0.v, o[vt], 0, 0, 0);
        o[vt] = __builtin_amdgcn_mfma_f32_32x32x16_bf16(vb, pu1.v, o[vt], 0, 0, 0);
      }
      // lsum += kpm_row . P  (masked row-sum on the matrix pipe)
      lacc = __builtin_amdgcn_mfma_f32_32x32x16_bf16(lva0, pu0.v, lacc, 0, 0, 0);
      lacc = __builtin_amdgcn_mfma_f32_32x32x16_bf16(lva1, pu1.v, lacc, 0, 0, 0);
    }
    // Raw barrier: drain LDS ops only; prefetch global loads stay in flight.
    // dbuf safety: reads of buf[cur] complete before this barrier; writes to
    // buf[cur] happen only after it (next iteration).
    __builtin_amdgcn_sched_barrier(0);
    asm volatile("s_waitcnt lgkmcnt(0)" ::: "memory");
    __builtin_amdgcn_s_barrier();
    __builtin_amdgcn_sched_barrier(0);
  }

  // ---- epilogue: lacc already holds full masked row-sum for q = col = ln ----
  float invl = 1.0f / lacc[0];
  size_t orow = ((size_t)(bh * S_Q + qln)) * D_K;
#pragma unroll
  for (int vt = 0; vt < 4; vt++) {
#pragma unroll
    for (int qd = 0; qd < 4; qd++) {
      float4 vv;
      vv.x = o[vt][4 * qd + 0] * invl;
      vv.y = o[vt][4 * qd + 1] * invl;
      vv.z = o[vt][4 * qd + 2] * invl;
      vv.w = o[vt][4 * qd + 3] * invl;
      *(float4*)&out[orow + vt * 32 + qd * 8 + 4 * h] = vv;
    }
  }
}

extern "C" void kernel_launch(void* const* d_in, const int* in_sizes, int n_in,
                              void* d_out, int out_size, void* d_ws, size_t ws_size,
                              hipStream_t stream) {
  const float* Q = (const float*)d_in[0];
  const float* K = (const float*)d_in[1];
  const float* V = (const float*)d_in[2];
  const int* kpm = (const int*)d_in[3];
  float* out = (float*)d_out;
  hipLaunchKernelGGL(prep_k_kernel, dim3(8192), dim3(256), 0, stream, K, kpm);
  hipLaunchKernelGGL(prep_v_kernel, dim3(8192), dim3(256), 0, stream, V, kpm);
  hipLaunchKernelGGL(attn_kernel, dim3(1024), dim3(256), 0, stream, Q, out);
}

// Round 3
// 306.648 us; speedup vs baseline: 1.1804x; 1.1804x over previous
//
#include <hip/hip_runtime.h>

#define S_Q 2048
#define S_KV 2048
#define D_K 128
#define NH 64
#define NB 4
// (1/sqrt(128)) * log2(e): fold softmax scale AND exp->exp2 conversion into Q
#define QSCALE 0.12751494907890272f

typedef __attribute__((ext_vector_type(8))) short s16x8;
typedef __attribute__((ext_vector_type(16))) float f32x16;

__device__ __attribute__((aligned(16))) unsigned short g_Kb[(size_t)NH * S_KV * D_K];
__device__ __attribute__((aligned(16))) unsigned short g_Vt[(size_t)NH * D_K * S_KV];

__device__ inline unsigned short f2bf(float f) {
  unsigned int u = __float_as_uint(f);
  u += 0x7FFFu + ((u >> 16) & 1u);  // RNE
  return (unsigned short)(u >> 16);
}

// RNE pack two f32 -> one dword of 2x bf16 (lo = first arg)
__device__ inline unsigned cvt_pk_bf16(float lo, float hi) {
  unsigned r;
  asm("v_cvt_pk_bf16_f32 %0, %1, %2" : "=v"(r) : "v"(lo), "v"(hi));
  return r;
}

// v_permlane32_swap_b32: first.hi(lanes32-63) <-> second.lo(lanes0-31)
__device__ inline void plane32_swap(unsigned& a, unsigned& b) {
#if __has_builtin(__builtin_amdgcn_permlane32_swap)
  typedef unsigned __attribute__((ext_vector_type(2))) u32x2;
  u32x2 r = __builtin_amdgcn_permlane32_swap(a, b, false, false);
  a = r.x; b = r.y;
#else
  asm volatile("v_permlane32_swap_b32 %0, %1" : "+v"(a), "+v"(b));
#endif
}

// ---------------- merged prep: blocks [0,8192) = K cast; [8192,16384) = V transpose ----------------
__global__ __launch_bounds__(256) void prep_kernel(const float* __restrict__ K,
                                                   const float* __restrict__ V,
                                                   const int* __restrict__ kpm) {
  __shared__ float tile_f[64][33];
  const int bid = blockIdx.x;
  if (bid < 8192) {
    // K: fp32 -> bf16, same layout
    size_t g = (size_t)bid * 256 + threadIdx.x;
    const float* src = K + g * 8;
    float4 x = *(const float4*)src;
    float4 y = *(const float4*)(src + 4);
    union { uint4 q; unsigned short u[8]; } t;
    t.u[0] = f2bf(x.x); t.u[1] = f2bf(x.y); t.u[2] = f2bf(x.z); t.u[3] = f2bf(x.w);
    t.u[4] = f2bf(y.x); t.u[5] = f2bf(y.y); t.u[6] = f2bf(y.z); t.u[7] = f2bf(y.w);
    ((uint4*)g_Kb)[g] = t.q;
  } else {
    // V: fp32 -> bf16 transposed, kpm-masked rows zeroed. 64 t x 32 v tile per block.
    const int vb = bid - 8192;
    int bh = vb >> 7;
    int rem = vb & 127;
    int t0 = (rem >> 2) << 6;
    int v0 = (rem & 3) << 5;
    int c = threadIdx.x & 31;
    int r8 = threadIdx.x >> 5;  // 0..7
    const int* kp = kpm + (bh >> 4) * S_KV + t0;
#pragma unroll
    for (int i = 0; i < 8; i++) {
      int r = r8 + i * 8;
      float f = V[((size_t)(bh * S_KV + t0 + r)) * D_K + v0 + c];
      tile_f[r][c] = kp[r] ? f : 0.0f;  // fold key_padding_mask into V
    }
    __syncthreads();
    int vv = threadIdx.x >> 3;  // 0..31
    int jc = threadIdx.x & 7;   // 8-elem chunk along t
    union { uint4 q; unsigned short u[8]; } t;
#pragma unroll
    for (int u8 = 0; u8 < 8; u8++) t.u[u8] = f2bf(tile_f[jc * 8 + u8][vv]);
    *(uint4*)&g_Vt[((size_t)(bh * D_K + v0 + vv)) * S_KV + t0 + jc * 8] = t.q;
  }
}

// ---------------- main: flash attention, S^T formulation, dbuf ----------------
// Loop order: compute(buf[cur]) -> store_tile(1-cur) -> issue prefetch -> lgkm-only barrier.
// Prefetched global loads get a FULL iteration of compute as latency cover; no vmcnt(0)
// ever appears in the loop (store's implicit wait finds its loads already complete).
__global__ __launch_bounds__(256, 3) void attn_kernel(const float* __restrict__ Q,
                                                      const int* __restrict__ kpm,
                                                      float* __restrict__ out) {
  __shared__ __attribute__((aligned(16))) unsigned short sK[2][32 * 136];  // [t=32][k=128] pitch 136
  __shared__ __attribute__((aligned(16))) unsigned short sV[2][128 * 40];  // [v=128][t=32] pitch 40
  __shared__ unsigned sMask[64];  // kpm bitmask per 32-kv tile

  const int bx = blockIdx.x;
  const int bh = ((bx & 7) << 3) | ((bx >> 3) & 7);  // same-bh q-tiles share XCD
  int qp = bx >> 6;
  // pair long+short causal tiles across dispatch batches
  int qi = (qp & 4) ? ((qp & 8) ? qp - 8 : qp - 4) : ((qp & 8) ? 19 - qp : 15 - qp);
  const int q0 = qi << 7;
  const int tid = threadIdx.x;
  const int w = tid >> 6;
  const int ln = tid & 31;
  const int h = (tid >> 5) & 1;
  const int h8 = h * 8;
  const int qw = q0 + w * 32;
  const int qln = qw + ln;
  const int b = bh >> 4;

  // ---- kpm ballot -> sMask (one-time) ----
  {
    int base = w * 512;
#pragma unroll
    for (int rr = 0; rr < 8; rr++) {
      int idx = base + rr * 64 + (tid & 63);
      unsigned long long bal = __ballot(kpm[b * S_KV + idx] != 0);
      if ((tid & 63) == 0) {
        sMask[(base >> 5) + rr * 2] = (unsigned)bal;
        sMask[(base >> 5) + rr * 2 + 1] = (unsigned)(bal >> 32);
      }
    }
  }

  // ---- Q fragments (B-operand layout == A layout; scale*log2e folded) ----
  s16x8 qf[8];
  {
    const float* qrow = Q + ((size_t)(bh * S_Q + qln)) * D_K + h8;
#pragma unroll
    for (int kc = 0; kc < 8; kc++) {
      float4 x = *(const float4*)(qrow + kc * 16);
      float4 y = *(const float4*)(qrow + kc * 16 + 4);
      union { s16x8 v; unsigned short u[8]; } t;
      t.u[0] = f2bf(x.x * QSCALE); t.u[1] = f2bf(x.y * QSCALE);
      t.u[2] = f2bf(x.z * QSCALE); t.u[3] = f2bf(x.w * QSCALE);
      t.u[4] = f2bf(y.x * QSCALE); t.u[5] = f2bf(y.y * QSCALE);
      t.u[6] = f2bf(y.z * QSCALE); t.u[7] = f2bf(y.w * QSCALE);
      qf[kc] = t.v;
    }
  }

  // ---- staging helpers (each thread: 2 uint4 for K, 2 for V) ----
  const int id0 = tid, id1 = 256 + tid;
  const int kr0r = id0 >> 4, kr0c = (id0 & 15) * 8;
  const int kr1r = id1 >> 4, kr1c = (id1 & 15) * 8;
  const int vr0r = id0 >> 2, vr0c = (id0 & 3) * 8;
  const int vr1r = id1 >> 2, vr1c = (id1 & 3) * 8;
  uint4 rk0, rk1, rv0, rv1;
  auto load_tile = [&](int t0) {
    rk0 = *(const uint4*)&g_Kb[((size_t)(bh * S_KV + t0 + kr0r)) * D_K + kr0c];
    rk1 = *(const uint4*)&g_Kb[((size_t)(bh * S_KV + t0 + kr1r)) * D_K + kr1c];
    rv0 = *(const uint4*)&g_Vt[((size_t)(bh * D_K + vr0r)) * S_KV + t0 + vr0c];
    rv1 = *(const uint4*)&g_Vt[((size_t)(bh * D_K + vr1r)) * S_KV + t0 + vr1c];
  };
  auto store_tile = [&](int buf) {
    *(uint4*)&sK[buf][kr0r * 136 + kr0c] = rk0;
    *(uint4*)&sK[buf][kr1r * 136 + kr1c] = rk1;
    *(uint4*)&sV[buf][vr0r * 40 + vr0c] = rv0;
    *(uint4*)&sV[buf][vr1r * 40 + vr1c] = rv1;
  };

  f32x16 o[4] = {f32x16{}, f32x16{}, f32x16{}, f32x16{}};
  float lsum = 0.0f;

  const int nT = qi * 4 + 4;
  load_tile(0);
  store_tile(0);
  __syncthreads();  // buf0 + sMask ready (one-time full drain)
  load_tile(32);    // tile 1 in flight; consumed by store at END of iter 0

  for (int i = 0; i < nT; i++) {
    const int cur = i & 1;
    const int t0 = i * 32;
    if (t0 <= qw) {
      // S^T = K * Q^T  (A = K frag m=t, B = Q frag n=qrow)
      f32x16 sa = {};
#pragma unroll
      for (int kc = 0; kc < 8; kc++) {
        s16x8 kb = *(const s16x8*)&sK[cur][ln * 136 + kc * 16 + h8];
        sa = __builtin_amdgcn_mfma_f32_32x32x16_bf16(kb, qf[kc], sa, 0, 0, 0);
      }
      // combined causal + kpm 32-bit mask for this lane (qrow = qln)
      const unsigned km = sMask[i];
      int thr = qln - t0;
      unsigned causal = (thr >= 31) ? 0xFFFFFFFFu : ((thr < 0) ? 0u : ((2u << thr) - 1u));
      unsigned pmh = (km & causal) >> (h * 4);
      float p[16];
#pragma unroll
      for (int r = 0; r < 16; r++) {
        const int tb = (r & 3) + 8 * (r >> 2);  // t_local = tb + 4h
        float e = __builtin_amdgcn_exp2f(sa[r]);
        p[r] = ((pmh >> tb) & 1u) ? e : 0.0f;
        lsum += p[r];
      }
      // RNE pack to bf16 dwords, then half-wave swap -> P^T B-frags
      unsigned d[8];
#pragma unroll
      for (int m = 0; m < 4; m++) {
        d[2 * m] = cvt_pk_bf16(p[4 * m + 0], p[4 * m + 1]);
        d[2 * m + 1] = cvt_pk_bf16(p[4 * m + 2], p[4 * m + 3]);
      }
      plane32_swap(d[0], d[2]); plane32_swap(d[1], d[3]);
      plane32_swap(d[4], d[6]); plane32_swap(d[5], d[7]);
      union { unsigned u[4]; s16x8 v; } pu0, pu1;
      pu0.u[0] = d[0]; pu0.u[1] = d[1]; pu0.u[2] = d[2]; pu0.u[3] = d[3];
      pu1.u[0] = d[4]; pu1.u[1] = d[5]; pu1.u[2] = d[6]; pu1.u[3] = d[7];
      // O^T += V^T * P^T   (V already kpm-zeroed in prep)
#pragma unroll
      for (int vt = 0; vt < 4; vt++) {
        s16x8 va = *(const s16x8*)&sV[cur][(vt * 32 + ln) * 40 + h8];
        s16x8 vb = *(const s16x8*)&sV[cur][(vt * 32 + ln) * 40 + 16 + h8];
        o[vt] = __builtin_amdgcn_mfma_f32_32x32x16_bf16(va, pu0.v, o[vt], 0, 0, 0);
        o[vt] = __builtin_amdgcn_mfma_f32_32x32x16_bf16(vb, pu1.v, o[vt], 0, 0, 0);
      }
    }
    // Stage NEXT tile after compute: the loads it consumes were issued one full
    // iteration ago (vmcnt wait ~free), then issue the following prefetch.
    if (i + 1 < nT) {
      store_tile(1 - cur);
      if (i + 2 < nT) load_tile((i + 2) * 32);
    }
    // lgkm-only barrier: prefetch global loads stay in flight across it.
    // dbuf safety: iter i reads buf[cur] and writes buf[1-cur]; iter i+1's
    // overwrite of buf[cur] happens only after this barrier, by which point
    // every wave's reads have drained (lgkmcnt(0) precedes the signal).
    __builtin_amdgcn_sched_barrier(0);
    asm volatile("s_waitcnt lgkmcnt(0)" ::: "memory");
    __builtin_amdgcn_s_barrier();
  }

  // ---- epilogue: l across halves, normalize, float4 stores ----
  float ltot = lsum + __shfl_xor(lsum, 32, 64);
  float invl = 1.0f / ltot;
  size_t orow = ((size_t)(bh * S_Q + qln)) * D_K;
#pragma unroll
  for (int vt = 0; vt < 4; vt++) {
#pragma unroll
    for (int qd = 0; qd < 4; qd++) {
      float4 vv;
      vv.x = o[vt][4 * qd + 0] * invl;
      vv.y = o[vt][4 * qd + 1] * invl;
      vv.z = o[vt][4 * qd + 2] * invl;
      vv.w = o[vt][4 * qd + 3] * invl;
      *(float4*)&out[orow + vt * 32 + qd * 8 + 4 * h] = vv;
    }
  }
}

extern "C" void kernel_launch(void* const* d_in, const int* in_sizes, int n_in,
                              void* d_out, int out_size, void* d_ws, size_t ws_size,
                              hipStream_t stream) {
  const float* Q = (const float*)d_in[0];
  const float* K = (const float*)d_in[1];
  const float* V = (const float*)d_in[2];
  const int* kpm = (const int*)d_in[3];
  float* out = (float*)d_out;
  hipLaunchKernelGGL(prep_kernel, dim3(16384), dim3(256), 0, stream, K, V, kpm);
  hipLaunchKernelGGL(attn_kernel, dim3(1024), dim3(256), 0, stream, Q, kpm, out);
}